// Round 8
// baseline (171.867 us; speedup 1.0000x reference)
//
#include <hip/hip_runtime.h>

#define B_   16
#define C_   512
#define HW_  1024
#define G_   32
#define CPG  16
#define EPS  1e-5f
#define CHW  ((size_t)C_ * HW_)        // 524288 elements per batch (c,hw)
#define HW2  ((size_t)HW_ * HW_)       // 1048576 elements per batch (hw,hw)
#define SCALE 0.044194173824159216f    // 512^-0.5

typedef __attribute__((ext_vector_type(8))) short bf16x8;
typedef __attribute__((ext_vector_type(4))) float f32x4;

__device__ inline unsigned short f2bf(float f) {
    union { float f; unsigned u; } v; v.f = f;
    unsigned r = v.u + 0x7fffu + ((v.u >> 16) & 1u);   // RNE
    return (unsigned short)(r >> 16);
}
__device__ inline float bf2f(unsigned short h) {
    union { unsigned u; float f; } v; v.u = (unsigned)h << 16;
    return v.f;
}

__device__ inline void gload_lds16(const void* g, void* lds) {
    __builtin_amdgcn_global_load_lds(
        (const __attribute__((address_space(1))) void*)g,
        (__attribute__((address_space(3))) void*)lds,
        16, 0, 0);
}

// ---------------- fp32 -> bf16 weight convert (all 4 weights, one launch) ----
__global__ __launch_bounds__(256) void f2bf4_kernel(
    const float* __restrict__ w0, const float* __restrict__ w1,
    const float* __restrict__ w2, const float* __restrict__ w3,
    unsigned short* __restrict__ o0, unsigned short* __restrict__ o1,
    unsigned short* __restrict__ o2, unsigned short* __restrict__ o3)
{
    int wsel = blockIdx.x >> 8;
    int blk  = blockIdx.x & 255;
    const float* in = (wsel == 0) ? w0 : (wsel == 1) ? w1 : (wsel == 2) ? w2 : w3;
    unsigned short* out = (wsel == 0) ? o0 : (wsel == 1) ? o1 : (wsel == 2) ? o2 : o3;
    int i = (blk * 256 + threadIdx.x) * 4;
    float4 f = *reinterpret_cast<const float4*>(in + i);
    ushort4 o;
    o.x = f2bf(f.x); o.y = f2bf(f.y); o.z = f2bf(f.z); o.w = f2bf(f.w);
    *reinterpret_cast<ushort4*>(out + i) = o;
}

// ---------------- concat bq||bk -> bqk[1024] ----------------
__global__ __launch_bounds__(256) void bias_concat(
    const float* __restrict__ bq, const float* __restrict__ bk,
    float* __restrict__ bqk)
{
    const float* src = blockIdx.x ? bk : bq;
    bqk[blockIdx.x * 512 + threadIdx.x]       = src[threadIdx.x];
    bqk[blockIdx.x * 512 + 256 + threadIdx.x] = src[256 + threadIdx.x];
}

// ---------------- GN pass 1: per-(b,g) mean / rsqrt(var) ----------------
__global__ __launch_bounds__(256) void gn_stats(const float* __restrict__ x,
                                                float2* __restrict__ stats)
{
    int bg = blockIdx.x;                                  // 0..511
    const float4* xp = reinterpret_cast<const float4*>(x + (size_t)bg * CPG * HW_);
    const int N = CPG * HW_;                              // 16384

    float s = 0.f, ss = 0.f;
#pragma unroll
    for (int k = 0; k < 16; ++k) {
        float4 v = xp[threadIdx.x + k * 256];
        s  += v.x + v.y + v.z + v.w;
        ss += v.x * v.x + v.y * v.y + v.z * v.z + v.w * v.w;
    }
    for (int off = 32; off; off >>= 1) {
        s  += __shfl_down(s,  off, 64);
        ss += __shfl_down(ss, off, 64);
    }
    __shared__ float red0[4], red1[4];
    int lane = threadIdx.x & 63, wid = threadIdx.x >> 6;
    if (lane == 0) { red0[wid] = s; red1[wid] = ss; }
    __syncthreads();
    if (threadIdx.x == 0) {
        float S  = red0[0] + red0[1] + red0[2] + red0[3];
        float SS = red1[0] + red1[1] + red1[2] + red1[3];
        float mu = S / (float)N;
        float var = SS / (float)N - mu * mu;
        stats[bg] = make_float2(mu, rsqrtf(var + EPS));
    }
}

// ---------------- GN pass 2: normalize + transpose -> bf16 hn_t[b][i][c] ----
__global__ __launch_bounds__(256) void gn_apply(
    const float* __restrict__ x, const float2* __restrict__ stats,
    const float* __restrict__ scale, const float* __restrict__ bias,
    unsigned short* __restrict__ hn_t)
{
    __shared__ unsigned short tile[64][72];

    const int b  = blockIdx.z;
    const int c0 = blockIdx.y * 64;
    const int i0 = blockIdx.x * 64;
    const int t  = threadIdx.x;

    const int r = t >> 2;
    const int q = t & 3;
    const int c = c0 + r;

    float2 st = stats[b * G_ + (c >> 4)];
    float scl = scale[c] * st.y;
    float bia = bias[c] - st.x * scl;

    const float* xp = x + ((size_t)b * C_ + c) * HW_ + i0 + q * 16;
#pragma unroll
    for (int u = 0; u < 4; ++u) {
        float4 v = *reinterpret_cast<const float4*>(xp + u * 4);
        int il = q * 16 + u * 4;
        tile[il + 0][r] = f2bf(v.x * scl + bia);
        tile[il + 1][r] = f2bf(v.y * scl + bia);
        tile[il + 2][r] = f2bf(v.z * scl + bia);
        tile[il + 3][r] = f2bf(v.w * scl + bia);
    }
    __syncthreads();

    const int il = t >> 2;
    unsigned short* dst = hn_t + ((size_t)b * HW_ + i0 + il) * C_ + c0;
    *reinterpret_cast<uint4*>(dst + q * 8)        = *reinterpret_cast<uint4*>(&tile[il][q * 8]);
    *reinterpret_cast<uint4*>(dst + (q + 4) * 8)  = *reinterpret_cast<uint4*>(&tile[il][(q + 4) * 8]);
}

// ================= 256x128 NT bf16 MFMA GEMM, 8-phase pipeline ==============
// (unchanged from round 7 — used for QK-proj, V-proj, O-proj)
template<int OUTF32, int BIASMODE, int HASRES>
__global__ __launch_bounds__(512) void gemm_8p(
    const short* __restrict__ A, size_t sA, int ldA,
    const short* __restrict__ Bm, size_t sB, int ldB,
    void* __restrict__ Cm, size_t sC, int ldC,
    const float* __restrict__ bias,
    const float* __restrict__ res, size_t sR,
    int K, float alpha)
{
    __shared__ __align__(16) short lds[49152];    // 96 KB

    const int bz = blockIdx.z;
    const short* Ab = A  + (size_t)bz * sA;
    const short* Bb = Bm + (size_t)bz * sB;
    const int m0 = blockIdx.y * 256;
    const int n0 = blockIdx.x * 128;

    const int t = threadIdx.x;
    const int wv = t >> 6, lane = t & 63;
    const int wm = wv >> 1, wn = wv & 1;
    const int fr = lane & 15;
    const int cb = (lane >> 4) * 16;

    size_t srcA0, srcA1, srcB;
    {
        int p0 = t * 16;
        int a0 = p0 ^ (((p0 >> 7) & 3) << 4);
        srcA0 = (size_t)(m0 + (a0 >> 6)) * ldA + ((a0 & 63) >> 1);
        int p1 = 8192 + t * 16;
        int a1 = p1 ^ (((p1 >> 7) & 3) << 4);
        srcA1 = (size_t)(m0 + (a1 >> 6)) * ldA + ((a1 & 63) >> 1);
        srcB  = (size_t)(n0 + (a0 >> 6)) * ldB + ((a0 & 63) >> 1);
    }
    auto stageA = [&](int par, int kh, int kt_src) {
        const short* s = Ab + kt_src * 64 + kh * 32;
        short* d = &lds[(par * 2 + kh) * 8192 + wv * 512];
        gload_lds16(s + srcA0, d);
        gload_lds16(s + srcA1, d + 4096);
    };
    auto stageB = [&](int par, int kh, int kt_src) {
        const short* s = Bb + kt_src * 64 + kh * 32;
        gload_lds16(s + srcB, &lds[32768 + (par * 2 + kh) * 4096 + wv * 512]);
    };

    int aoffs[4], boffs[4];
#pragma unroll
    for (int fi = 0; fi < 4; ++fi) {
        int row = wm * 64 + fi * 16 + fr;
        int off = row * 64 + cb;
        aoffs[fi] = off ^ (((off >> 7) & 3) << 4);
    }
#pragma unroll
    for (int fj = 0; fj < 4; ++fj) {
        int row = wn * 64 + fj * 16 + fr;
        int off = row * 64 + cb;
        boffs[fj] = off ^ (((off >> 7) & 3) << 4);
    }

    f32x4 acc[4][4];
#pragma unroll
    for (int i = 0; i < 4; ++i)
#pragma unroll
        for (int j = 0; j < 4; ++j) acc[i][j] = (f32x4){0.f, 0.f, 0.f, 0.f};

    const int NT = K >> 6;
    const char* L = (const char*)lds;

    stageA(0, 0, 0); stageB(0, 0, 0);
    stageA(0, 1, 0); stageB(0, 1, 0);
    stageA(1, 0, 1); stageB(1, 0, 1);

    for (int kt = 0; kt < NT; ++kt) {
        const int par = kt & 1;
        const int AB0 = (par * 2) * 16384;
        const int AB1 = AB0 + 16384;
        const int BB0 = 65536 + (par * 2) * 8192;
        const int BB1 = BB0 + 8192;

        bf16x8 af0, af1, af2, af3, bf0, bf1;

        if (kt == NT - 1) asm volatile("s_waitcnt vmcnt(3)\n\ts_barrier" ::: "memory");
        else              asm volatile("s_waitcnt vmcnt(6)\n\ts_barrier" ::: "memory");
        af0 = *(const bf16x8*)(L + AB0 + aoffs[0]);
        af1 = *(const bf16x8*)(L + AB0 + aoffs[1]);
        af2 = *(const bf16x8*)(L + AB0 + aoffs[2]);
        af3 = *(const bf16x8*)(L + AB0 + aoffs[3]);
        bf0 = *(const bf16x8*)(L + BB0 + boffs[0]);
        bf1 = *(const bf16x8*)(L + BB0 + boffs[1]);
        if (kt + 1 < NT) stageA(par ^ 1, 1, kt + 1);
        __builtin_amdgcn_s_setprio(1);
        acc[0][0] = __builtin_amdgcn_mfma_f32_16x16x32_bf16(af0, bf0, acc[0][0], 0, 0, 0);
        acc[1][0] = __builtin_amdgcn_mfma_f32_16x16x32_bf16(af1, bf0, acc[1][0], 0, 0, 0);
        acc[2][0] = __builtin_amdgcn_mfma_f32_16x16x32_bf16(af2, bf0, acc[2][0], 0, 0, 0);
        acc[3][0] = __builtin_amdgcn_mfma_f32_16x16x32_bf16(af3, bf0, acc[3][0], 0, 0, 0);
        acc[0][1] = __builtin_amdgcn_mfma_f32_16x16x32_bf16(af0, bf1, acc[0][1], 0, 0, 0);
        acc[1][1] = __builtin_amdgcn_mfma_f32_16x16x32_bf16(af1, bf1, acc[1][1], 0, 0, 0);
        acc[2][1] = __builtin_amdgcn_mfma_f32_16x16x32_bf16(af2, bf1, acc[2][1], 0, 0, 0);
        acc[3][1] = __builtin_amdgcn_mfma_f32_16x16x32_bf16(af3, bf1, acc[3][1], 0, 0, 0);
        __builtin_amdgcn_s_setprio(0);
        asm volatile("s_waitcnt lgkmcnt(0)\n\ts_barrier" ::: "memory");

        bf0 = *(const bf16x8*)(L + BB0 + boffs[2]);
        bf1 = *(const bf16x8*)(L + BB0 + boffs[3]);
        if (kt + 1 < NT) stageB(par ^ 1, 1, kt + 1);
        __builtin_amdgcn_s_setprio(1);
        acc[0][2] = __builtin_amdgcn_mfma_f32_16x16x32_bf16(af0, bf0, acc[0][2], 0, 0, 0);
        acc[1][2] = __builtin_amdgcn_mfma_f32_16x16x32_bf16(af1, bf0, acc[1][2], 0, 0, 0);
        acc[2][2] = __builtin_amdgcn_mfma_f32_16x16x32_bf16(af2, bf0, acc[2][2], 0, 0, 0);
        acc[3][2] = __builtin_amdgcn_mfma_f32_16x16x32_bf16(af3, bf0, acc[3][2], 0, 0, 0);
        acc[0][3] = __builtin_amdgcn_mfma_f32_16x16x32_bf16(af0, bf1, acc[0][3], 0, 0, 0);
        acc[1][3] = __builtin_amdgcn_mfma_f32_16x16x32_bf16(af1, bf1, acc[1][3], 0, 0, 0);
        acc[2][3] = __builtin_amdgcn_mfma_f32_16x16x32_bf16(af2, bf1, acc[2][3], 0, 0, 0);
        acc[3][3] = __builtin_amdgcn_mfma_f32_16x16x32_bf16(af3, bf1, acc[3][3], 0, 0, 0);
        __builtin_amdgcn_s_setprio(0);
        asm volatile("s_waitcnt lgkmcnt(0)\n\ts_barrier" ::: "memory");

        if (kt == NT - 1) asm volatile("s_waitcnt vmcnt(0)\n\ts_barrier" ::: "memory");
        else              asm volatile("s_waitcnt vmcnt(6)\n\ts_barrier" ::: "memory");
        af0 = *(const bf16x8*)(L + AB1 + aoffs[0]);
        af1 = *(const bf16x8*)(L + AB1 + aoffs[1]);
        af2 = *(const bf16x8*)(L + AB1 + aoffs[2]);
        af3 = *(const bf16x8*)(L + AB1 + aoffs[3]);
        bf0 = *(const bf16x8*)(L + BB1 + boffs[0]);
        bf1 = *(const bf16x8*)(L + BB1 + boffs[1]);
        if (kt + 2 < NT) stageA(par, 0, kt + 2);
        __builtin_amdgcn_s_setprio(1);
        acc[0][0] = __builtin_amdgcn_mfma_f32_16x16x32_bf16(af0, bf0, acc[0][0], 0, 0, 0);
        acc[1][0] = __builtin_amdgcn_mfma_f32_16x16x32_bf16(af1, bf0, acc[1][0], 0, 0, 0);
        acc[2][0] = __builtin_amdgcn_mfma_f32_16x16x32_bf16(af2, bf0, acc[2][0], 0, 0, 0);
        acc[3][0] = __builtin_amdgcn_mfma_f32_16x16x32_bf16(af3, bf0, acc[3][0], 0, 0, 0);
        acc[0][1] = __builtin_amdgcn_mfma_f32_16x16x32_bf16(af0, bf1, acc[0][1], 0, 0, 0);
        acc[1][1] = __builtin_amdgcn_mfma_f32_16x16x32_bf16(af1, bf1, acc[1][1], 0, 0, 0);
        acc[2][1] = __builtin_amdgcn_mfma_f32_16x16x32_bf16(af2, bf1, acc[2][1], 0, 0, 0);
        acc[3][1] = __builtin_amdgcn_mfma_f32_16x16x32_bf16(af3, bf1, acc[3][1], 0, 0, 0);
        __builtin_amdgcn_s_setprio(0);
        asm volatile("s_waitcnt lgkmcnt(0)\n\ts_barrier" ::: "memory");

        bf0 = *(const bf16x8*)(L + BB1 + boffs[2]);
        bf1 = *(const bf16x8*)(L + BB1 + boffs[3]);
        if (kt + 2 < NT) stageB(par, 0, kt + 2);
        __builtin_amdgcn_s_setprio(1);
        acc[0][2] = __builtin_amdgcn_mfma_f32_16x16x32_bf16(af0, bf0, acc[0][2], 0, 0, 0);
        acc[1][2] = __builtin_amdgcn_mfma_f32_16x16x32_bf16(af1, bf0, acc[1][2], 0, 0, 0);
        acc[2][2] = __builtin_amdgcn_mfma_f32_16x16x32_bf16(af2, bf0, acc[2][2], 0, 0, 0);
        acc[3][2] = __builtin_amdgcn_mfma_f32_16x16x32_bf16(af3, bf0, acc[3][2], 0, 0, 0);
        acc[0][3] = __builtin_amdgcn_mfma_f32_16x16x32_bf16(af0, bf1, acc[0][3], 0, 0, 0);
        acc[1][3] = __builtin_amdgcn_mfma_f32_16x16x32_bf16(af1, bf1, acc[1][3], 0, 0, 0);
        acc[2][3] = __builtin_amdgcn_mfma_f32_16x16x32_bf16(af2, bf1, acc[2][3], 0, 0, 0);
        acc[3][3] = __builtin_amdgcn_mfma_f32_16x16x32_bf16(af3, bf1, acc[3][3], 0, 0, 0);
        __builtin_amdgcn_s_setprio(0);
        asm volatile("s_waitcnt lgkmcnt(0)\n\ts_barrier" ::: "memory");
    }

    const int rq = (lane >> 4) * 4;
#pragma unroll
    for (int fi = 0; fi < 4; ++fi) {
#pragma unroll
        for (int rg = 0; rg < 4; ++rg) {
            int row = m0 + wm * 64 + fi * 16 + rq + rg;
            float bm = (BIASMODE == 1) ? bias[row] : 0.f;
#pragma unroll
            for (int fj = 0; fj < 4; ++fj) {
                int col = n0 + wn * 64 + fj * 16 + fr;
                float vv = acc[fi][fj][rg] * alpha + bm;
                if (BIASMODE == 2) vv += bias[col];
                size_t off = (size_t)row * ldC + col;
                if (HASRES) vv += res[(size_t)bz * sR + off];
                if (OUTF32) ((float*)Cm)[(size_t)bz * sC + off] = vv;
                else ((unsigned short*)Cm)[(size_t)bz * sC + off] = f2bf(vv);
            }
        }
    }
}

// ================= fused flash attention =====================================
// grid 256: wg -> (b = wg&15, qb = wg>>4) so same-batch blocks share an XCD.
// 8 waves, QB=64, KB=64, D=512, 16 KV iters.
// QK^T: wave w computes S rows [(w>>1)*16..+16) x j-cols [(w&1)*32..+32);
//       Q frags resident in VGPRs (16 k-steps), K staged LDS [64][512] swz.
// softmax: online (m,l per row in regs of owner wave-pair); cross-pair
//       exchange + alpha broadcast via small LDS; P bf16 -> swizzled LDS.
// PV: wave w owns O d-slice [w*64..+64): acc 4x4 frags; V staged LDS [512][64]
//       swz (from v[b][c][j], c-major rows are j-contiguous).
__global__ __launch_bounds__(512) void flash_attn(
    const short* __restrict__ qk_t,       // [b*1024][1024] = q||k
    const short* __restrict__ vsrc,       // [b][512][1024]
    unsigned short* __restrict__ ao_t)    // [b*1024][512]
{
    __shared__ __align__(16) short Klds[64 * 512];        // 64 KB [j][c] swz
    __shared__ __align__(16) short Vlds[512 * 64];        // 64 KB [c][j] swz
    __shared__ __align__(16) unsigned short Plds[64 * 64];// 8 KB  [q][j] swz
    __shared__ float smax[2][64], ssum[2][64], arow[64], lrow[64];

    const int wg = blockIdx.x;
    const int b  = wg & 15;
    const int qb = wg >> 4;
    const int t  = threadIdx.x;
    const int wv = t >> 6, lane = t & 63;
    const int l15 = lane & 15, l4 = lane >> 4;

    const short* Qg = qk_t + ((size_t)(b * 1024 + qb * 64)) * 1024;
    const short* Kg = qk_t + (size_t)(b * 1024) * 1024 + 512;
    const short* Vg = vsrc + (size_t)b * CHW;

    // Q frags resident: rows (wv>>1)*16 + l15, k = ks*32 + l4*8
    bf16x8 qf[16];
    {
        const short* qrow = Qg + (size_t)((wv >> 1) * 16 + l15) * 1024 + l4 * 8;
#pragma unroll
        for (int ks = 0; ks < 16; ++ks)
            qf[ks] = *(const bf16x8*)(qrow + ks * 32);
    }

    // K stage: dest row r*8+wv (linear), lane inner 16B; src col pre-swizzled
    auto stageK = [&](int tkv) {
        const short* src = Kg + (size_t)(tkv * 64) * 1024;
#pragma unroll
        for (int r = 0; r < 8; ++r)
            gload_lds16(src + (size_t)(r * 8 + wv) * 1024 + (lane ^ wv) * 8,
                        &Klds[r * 4096 + t * 8]);
    };
    // V stage: dest row c = r*64 + (t>>3), inner (t&7)*16B; src pre-swizzled
    auto stageV = [&](int tkv) {
        const short* src = Vg + tkv * 64;
#pragma unroll
        for (int r = 0; r < 8; ++r)
            gload_lds16(src + (size_t)(r * 64 + (t >> 3)) * 1024
                            + ((t & 7) ^ ((t >> 3) & 7)) * 8,
                        &Vlds[r * 4096 + t * 8]);
    };

    f32x4 acc[4][4];
#pragma unroll
    for (int i = 0; i < 4; ++i)
#pragma unroll
        for (int j = 0; j < 4; ++j) acc[i][j] = (f32x4){0.f, 0.f, 0.f, 0.f};
    float m_r[4], l_r[4];
#pragma unroll
    for (int rg = 0; rg < 4; ++rg) { m_r[rg] = -1e30f; l_r[rg] = 0.f; }

    const int qr = (wv >> 1) * 16 + l4 * 4;   // first row of this lane's regs
    const int jbase = (wv & 1) * 32;

    stageK(0); stageV(0);

    for (int tkv = 0; tkv < 16; ++tkv) {
        asm volatile("s_waitcnt vmcnt(0)\n\ts_barrier" ::: "memory");

        // ---- QK^T: S[16q x 32j] as two 16x16 frags
        f32x4 s0 = (f32x4){0.f,0.f,0.f,0.f}, s1 = (f32x4){0.f,0.f,0.f,0.f};
#pragma unroll
        for (int ks = 0; ks < 16; ++ks) {
            int r0 = jbase + l15;
            int r1 = r0 + 16;
            int kc = ks * 64 + l4 * 16;
            int sw = (l15 & 7) << 4;
            bf16x8 k0 = *(const bf16x8*)((const char*)Klds + r0 * 1024 + (kc ^ sw));
            bf16x8 k1 = *(const bf16x8*)((const char*)Klds + r1 * 1024 + (kc ^ sw));
            s0 = __builtin_amdgcn_mfma_f32_16x16x32_bf16(qf[ks], k0, s0, 0, 0, 0);
            s1 = __builtin_amdgcn_mfma_f32_16x16x32_bf16(qf[ks], k1, s1, 0, 0, 0);
        }

        // ---- row-max over this wave's 32 j (reduce across 16-lane group)
        float u0[4], u1[4], tm[4];
#pragma unroll
        for (int rg = 0; rg < 4; ++rg) {
            u0[rg] = s0[rg] * SCALE; u1[rg] = s1[rg] * SCALE;
            float mx = fmaxf(u0[rg], u1[rg]);
            mx = fmaxf(mx, __shfl_xor(mx, 1));
            mx = fmaxf(mx, __shfl_xor(mx, 2));
            mx = fmaxf(mx, __shfl_xor(mx, 4));
            mx = fmaxf(mx, __shfl_xor(mx, 8));
            tm[rg] = mx;
        }
        if (l15 == 0) {
#pragma unroll
            for (int rg = 0; rg < 4; ++rg) smax[wv & 1][qr + rg] = tm[rg];
        }
        asm volatile("s_waitcnt lgkmcnt(0)\n\ts_barrier" ::: "memory");
        if (tkv + 1 < 16) stageK(tkv + 1);        // K-buf dead after barrier

        // ---- online update for own rows
        float al[4];
#pragma unroll
        for (int rg = 0; rg < 4; ++rg) {
            float tmax = fmaxf(smax[0][qr + rg], smax[1][qr + rg]);
            float mn = fmaxf(m_r[rg], tmax);
            al[rg] = __expf(m_r[rg] - mn);
            m_r[rg] = mn;
        }
        float p0[4], p1[4], ps[4];
#pragma unroll
        for (int rg = 0; rg < 4; ++rg) {
            p0[rg] = __expf(u0[rg] - m_r[rg]);
            p1[rg] = __expf(u1[rg] - m_r[rg]);
            float s = p0[rg] + p1[rg];
            s += __shfl_xor(s, 1); s += __shfl_xor(s, 2);
            s += __shfl_xor(s, 4); s += __shfl_xor(s, 8);
            ps[rg] = s;
        }
        if (l15 == 0) {
#pragma unroll
            for (int rg = 0; rg < 4; ++rg) {
                ssum[wv & 1][qr + rg] = ps[rg];
                if ((wv & 1) == 0) arow[qr + rg] = al[rg];
            }
        }
        // P -> bf16, swizzled LDS
#pragma unroll
        for (int rg = 0; rg < 4; ++rg) {
            int row = qr + rg;
            int sw = (row & 7) << 4;
            *(unsigned short*)((char*)Plds + row * 128 + (((jbase + l15) * 2) ^ sw)) = f2bf(p0[rg]);
            *(unsigned short*)((char*)Plds + row * 128 + (((jbase + 16 + l15) * 2) ^ sw)) = f2bf(p1[rg]);
        }
        asm volatile("s_waitcnt lgkmcnt(0)\n\ts_barrier" ::: "memory");

        // ---- l update, O-rescale (alpha for ALL 64 rows via LDS broadcast)
#pragma unroll
        for (int rg = 0; rg < 4; ++rg)
            l_r[rg] = l_r[rg] * al[rg] + ssum[0][qr + rg] + ssum[1][qr + rg];
        float af_[4][4];
#pragma unroll
        for (int fi = 0; fi < 4; ++fi)
#pragma unroll
            for (int rg = 0; rg < 4; ++rg)
                af_[fi][rg] = arow[fi * 16 + l4 * 4 + rg];
#pragma unroll
        for (int fi = 0; fi < 4; ++fi)
#pragma unroll
            for (int fj = 0; fj < 4; ++fj)
#pragma unroll
                for (int rg = 0; rg < 4; ++rg)
                    acc[fi][fj][rg] *= af_[fi][rg];

        // ---- PV: O[64q x 64d(slice wv)] += P x V
#pragma unroll
        for (int ks = 0; ks < 2; ++ks) {
            int kc = ks * 64 + l4 * 16;
            bf16x8 pf[4], vf[4];
#pragma unroll
            for (int fi = 0; fi < 4; ++fi) {
                int row = fi * 16 + l15;
                pf[fi] = *(const bf16x8*)((const char*)Plds + row * 128 + (kc ^ ((row & 7) << 4)));
            }
#pragma unroll
            for (int fj = 0; fj < 4; ++fj) {
                int dr = wv * 64 + fj * 16 + l15;
                vf[fj] = *(const bf16x8*)((const char*)Vlds + dr * 128 + (kc ^ ((dr & 7) << 4)));
            }
#pragma unroll
            for (int fi = 0; fi < 4; ++fi)
#pragma unroll
                for (int fj = 0; fj < 4; ++fj)
                    acc[fi][fj] = __builtin_amdgcn_mfma_f32_16x16x32_bf16(pf[fi], vf[fj], acc[fi][fj], 0, 0, 0);
        }
        asm volatile("s_waitcnt lgkmcnt(0)\n\ts_barrier" ::: "memory");
        if (tkv + 1 < 16) stageV(tkv + 1);        // V-buf dead after barrier
    }

    // ---- epilogue: divide by l, write ao_t[i][c]
    if ((wv & 1) == 0 && l15 == 0) {
#pragma unroll
        for (int rg = 0; rg < 4; ++rg) lrow[qr + rg] = 1.0f / l_r[rg];
    }
    asm volatile("s_waitcnt lgkmcnt(0)\n\ts_barrier" ::: "memory");
    float li[4][4];
#pragma unroll
    for (int fi = 0; fi < 4; ++fi)
#pragma unroll
        for (int rg = 0; rg < 4; ++rg) li[fi][rg] = lrow[fi * 16 + l4 * 4 + rg];

    unsigned short* aob = ao_t + ((size_t)(b * 1024 + qb * 64)) * 512 + wv * 64;
#pragma unroll
    for (int fi = 0; fi < 4; ++fi)
#pragma unroll
        for (int rg = 0; rg < 4; ++rg) {
            int row = fi * 16 + l4 * 4 + rg;
#pragma unroll
            for (int fj = 0; fj < 4; ++fj)
                aob[(size_t)row * 512 + fj * 16 + l15] = f2bf(acc[fi][fj][rg] * li[fi][rg]);
        }
}

extern "C" void kernel_launch(void* const* d_in, const int* in_sizes, int n_in,
                              void* d_out, int out_size, void* d_ws, size_t ws_size,
                              hipStream_t stream)
{
    const float* x        = (const float*)d_in[0];
    // d_in[1] = temb : unused by the reference
    const float* gn_scale = (const float*)d_in[2];
    const float* gn_bias  = (const float*)d_in[3];
    const float* wq = (const float*)d_in[4];
    const float* bq = (const float*)d_in[5];
    const float* wk = (const float*)d_in[6];
    const float* bk = (const float*)d_in[7];
    const float* wv = (const float*)d_in[8];
    const float* bv = (const float*)d_in[9];
    const float* wo = (const float*)d_in[10];
    const float* bo = (const float*)d_in[11];
    float* out = (float*)d_out;

    // workspace layout (bf16 elements)
    short* ws = (short*)d_ws;
    const size_t E = (size_t)B_ * C_ * HW_;        // 8388608
    short* hn_t = ws;                              // [b][i][c]          E
    short* qk_t = hn_t + E;                        // [b*i][q||k]        2E
    short* v    = qk_t + 2 * E;                    // [b][c][j]          E
    short* ao_t = v + E;                           // [b][i][c]          E
    short* attn = ao_t + E;                        // (unused now)       2E
    short* wsq  = attn + 2 * E;                    // wq||wk||wv||wo bf16
    short* wsk  = wsq + (size_t)C_ * C_;
    short* wsv  = wsk + (size_t)C_ * C_;
    short* wso  = wsv + (size_t)C_ * C_;
    float* bqk  = (float*)(wso + (size_t)C_ * C_); // 1024 f32
    float2* stats = (float2*)(bqk + 1024);         // 512 float2

    f2bf4_kernel<<<dim3(1024), 256, 0, stream>>>(
        wq, wk, wv, wo,
        (unsigned short*)wsq, (unsigned short*)wsk,
        (unsigned short*)wsv, (unsigned short*)wso);
    bias_concat<<<dim3(2), 256, 0, stream>>>(bq, bk, bqk);

    gn_stats<<<dim3(B_ * G_), 256, 0, stream>>>(x, stats);
    gn_apply<<<dim3(HW_ / 64, C_ / 64, B_), 256, 0, stream>>>(
        x, stats, gn_scale, gn_bias, (unsigned short*)hn_t);

    // fused QK projection: qk_t[m][n] = sum_c hn_t[m][c] * (wq||wk)[n][c] + bqk[n]
    dim3 gqk(HW_ / 128, (B_ * HW_) / 256, 1);      // (8, 64, 1)
    gemm_8p<0, 2, 0><<<gqk, 512, 0, stream>>>(
        hn_t, 0, C_, wsq, 0, C_, qk_t, 0, HW_, bqk, nullptr, 0, C_, 1.0f);

    // v[c][j] = sum_k wv[c][k] * hn_t[j][k] + bv[c]
    dim3 gv(HW_ / 128, C_ / 256, B_);              // (8, 2, 16)
    gemm_8p<0, 1, 0><<<gv, 512, 0, stream>>>(
        wsv, 0, C_, hn_t, CHW, C_, v, CHW, HW_, bv, nullptr, 0, C_, 1.0f);

    // fused attention: scores + softmax + PV  ->  ao_t[i][c]
    flash_attn<<<dim3(256), 512, 0, stream>>>(qk_t, v, (unsigned short*)ao_t);

    // out[c][i] = x + sum_k wo[c][k] * ao_t[i][k] + bo[c]
    dim3 go(HW_ / 128, C_ / 256, B_);              // (8, 2, 16)
    gemm_8p<1, 1, 1><<<go, 512, 0, stream>>>(
        wso, 0, C_, ao_t, CHW, C_, out, CHW, HW_, bo, x, CHW, C_, 1.0f);
}